// Round 2
// baseline (5772.362 us; speedup 1.0000x reference)
//
#include <hip/hip_runtime.h>
#include <hip/hip_bf16.h>

// Problem constants (from reference): S=512, B=256, E=256, H=256, V=50000
#define SS 512
#define BB 256
#define EE 256
#define HH 256
#define VV 50000
#define NCH 512          // 512 independent chains = 256 batch x 2 towers
#define NB 4             // chains per workgroup
#define NWG (NCH / NB)   // 128 workgroups
#define VR 16            // emb rows per block in embw GEMM

__device__ __forceinline__ float sigf(float x) { return 1.f / (1.f + __expf(-x)); }
__device__ __forceinline__ float tanhf_fast(float x) { return 1.f - 2.f / (__expf(2.f * x) + 1.f); }

// Pack W[4H][K] row-major into Wp[k][t] = float4{W[t][k], W[H+t][k], W[2H+t][k], W[3H+t][k]}
// -> thread t does ONE coalesced float4 load per k covering all 4 gates of unit t.
__global__ void pack_w4(const float* __restrict__ W, float4* __restrict__ Wp, int K) {
    int idx = blockIdx.x * blockDim.x + threadIdx.x;  // K*256 entries
    if (idx >= K * HH) return;
    int k = idx >> 8, t = idx & 255;
    Wp[idx] = make_float4(W[(0 * HH + t) * K + k], W[(1 * HH + t) * K + k],
                          W[(2 * HH + t) * K + k], W[(3 * HH + t) * K + k]);
}

__global__ void pack_b(const float* __restrict__ bi, const float* __restrict__ bh,
                       float4* __restrict__ bp) {
    int t = threadIdx.x;
    bp[t] = make_float4(bi[0 * HH + t] + bh[0 * HH + t], bi[1 * HH + t] + bh[1 * HH + t],
                        bi[2 * HH + t] + bh[2 * HH + t], bi[3 * HH + t] + bh[3 * HH + t]);
}

// W1 is [H][2H]; W1T[k][j] = W1[j][k] so head threads read coalesced.
__global__ void transpose_w1(const float* __restrict__ W1, float* __restrict__ W1T) {
    int idx = blockIdx.x * blockDim.x + threadIdx.x;  // 512*256
    if (idx >= 2 * HH * HH) return;
    int k = idx >> 8, j = idx & 255;
    W1T[idx] = W1[j * (2 * HH) + k];
}

// embWp[v][t] = float4 over 4 gates of (emb[v] @ W_ih^T + b_ih + b_hh)
__global__ __launch_bounds__(256) void embw_kernel(const float* __restrict__ emb,
                                                   const float4* __restrict__ Wip,
                                                   const float4* __restrict__ bp,
                                                   float4* __restrict__ embWp) {
    __shared__ float se[VR][EE];
    int t = threadIdx.x;
    int v0 = blockIdx.x * VR;
    for (int r = 0; r < VR; ++r) se[r][t] = emb[(size_t)(v0 + r) * EE + t];
    __syncthreads();
    float4 bb = bp[t];
    float4 acc[VR];
#pragma unroll
    for (int r = 0; r < VR; ++r) acc[r] = bb;
#pragma unroll 2
    for (int k = 0; k < EE; ++k) {
        float4 w = Wip[k * HH + t];
#pragma unroll
        for (int r = 0; r < VR; ++r) {
            float x = se[r][k];
            acc[r].x += w.x * x; acc[r].y += w.y * x;
            acc[r].z += w.z * x; acc[r].w += w.w * x;
        }
    }
    for (int r = 0; r < VR; ++r) embWp[(size_t)(v0 + r) * HH + t] = acc[r];
}

// Core recurrent kernel. One WG = NB chains; thread t owns hidden unit t of each chain
// (gate rows t, 256+t, 512+t, 768+t -> the c/h update is thread-local).
// PRE=true: input projection gathered from precomputed embWp (prefetched 1 step ahead).
// PRE=false: x-projection computed on the fly (ws too small for the 205MB table).
template <bool PRE>
__global__ __launch_bounds__(256, 1) void lstm_kernel(
    const int* __restrict__ s1, const int* __restrict__ s2, const float* __restrict__ emb,
    const float4* __restrict__ Whp, const float4* __restrict__ Wip,
    const float4* __restrict__ bp, const float4* __restrict__ embWp,
    const float* __restrict__ h0_1, const float* __restrict__ c0_1,
    const float* __restrict__ h0_2, const float* __restrict__ c0_2,
    float* __restrict__ feat) {
    __shared__ float hs[NB][HH];
    __shared__ int tok_lds[SS * NB];
    int t = threadIdx.x;
    int ch0 = blockIdx.x * NB;

    float c[NB];
    int bat[NB];
    const int* toks[NB];
#pragma unroll
    for (int nb = 0; nb < NB; ++nb) {
        int ch = ch0 + nb;
        bool t2 = ch >= BB;
        int b = t2 ? ch - BB : ch;
        bat[nb] = b;
        toks[nb] = t2 ? s2 : s1;
        const float* h0 = t2 ? h0_2 : h0_1;
        const float* cc0 = t2 ? c0_2 : c0_1;
        hs[nb][t] = h0[b * HH + t];
        c[nb] = cc0[b * HH + t];
    }
    // Preload all token indices for this WG's chains into LDS (removes a
    // dependent scattered load from every step's critical path).
    for (int idx = t; idx < SS * NB; idx += 256) {
        int s = idx >> 2, nb = idx & 3;
        tok_lds[idx] = toks[nb][s * BB + bat[nb]];
    }
    __syncthreads();

    float4 pf[NB];  // software-prefetched x-projection row for the NEXT step
    if constexpr (PRE) {
#pragma unroll
        for (int nb = 0; nb < NB; ++nb)
            pf[nb] = embWp[(size_t)tok_lds[nb] * HH + t];
    }

    for (int s = 0; s < SS; ++s) {
        float4 acc[NB];
        if constexpr (PRE) {
#pragma unroll
            for (int nb = 0; nb < NB; ++nb) acc[nb] = pf[nb];
            if (s + 1 < SS) {
                // Issue next step's gather now; it retires (vmcnt FIFO) under
                // the ~8K cycles of Whh FMAs below.
#pragma unroll
                for (int nb = 0; nb < NB; ++nb)
                    pf[nb] = embWp[(size_t)tok_lds[(s + 1) * NB + nb] * HH + t];
            }
        } else {
            __shared__ float xs[NB][EE];
            float4 bb = bp[t];
#pragma unroll
            for (int nb = 0; nb < NB; ++nb) {
                int tok = tok_lds[s * NB + nb];
                xs[nb][t] = emb[(size_t)tok * EE + t];
                acc[nb] = bb;
            }
            __syncthreads();
#pragma unroll 4
            for (int k = 0; k < EE; ++k) {
                float4 w = Wip[k * HH + t];
#pragma unroll
                for (int nb = 0; nb < NB; ++nb) {
                    float x = xs[nb][k];
                    acc[nb].x += w.x * x; acc[nb].y += w.y * x;
                    acc[nb].z += w.z * x; acc[nb].w += w.w * x;
                }
            }
        }
        // h @ W_hh^T : stream Whp (1MB, L2/L3-resident, shared by all WGs)
#pragma unroll 8
        for (int k = 0; k < HH; ++k) {
            float4 w = Whp[k * HH + t];
#pragma unroll
            for (int nb = 0; nb < NB; ++nb) {
                float hk = hs[nb][k];
                acc[nb].x += w.x * hk; acc[nb].y += w.y * hk;
                acc[nb].z += w.z * hk; acc[nb].w += w.w * hk;
            }
        }
        float hnew[NB];
#pragma unroll
        for (int nb = 0; nb < NB; ++nb) {
            float ig = sigf(acc[nb].x);
            float fg = sigf(acc[nb].y);
            float gg = tanhf_fast(acc[nb].z);
            float og = sigf(acc[nb].w);
            c[nb] = fg * c[nb] + ig * gg;
            hnew[nb] = og * tanhf_fast(c[nb]);
        }
        __syncthreads();  // all reads of hs (and xs) for step s done
#pragma unroll
        for (int nb = 0; nb < NB; ++nb) hs[nb][t] = hnew[nb];
        __syncthreads();
    }
#pragma unroll
    for (int nb = 0; nb < NB; ++nb) feat[(size_t)(ch0 + nb) * HH + t] = hs[nb][t];
}

// out[b] = (concat(v1[b], v2[b]) @ W1^T + b1) @ W2^T + b2
__global__ __launch_bounds__(256) void head_kernel(const float* __restrict__ feat,
                                                   const float* __restrict__ W1T,
                                                   const float* __restrict__ b1,
                                                   const float* __restrict__ W2,
                                                   const float* __restrict__ b2,
                                                   float* __restrict__ out) {
    __shared__ float f[2 * HH];
    __shared__ float r0[256], r1[256];
    int j = threadIdx.x;
    int b = blockIdx.x;
    f[j] = feat[(size_t)b * HH + j];
    f[HH + j] = feat[(size_t)(BB + b) * HH + j];
    __syncthreads();
    float acc = b1[j];
#pragma unroll 4
    for (int k = 0; k < 2 * HH; ++k) acc += f[k] * W1T[k * HH + j];
    r0[j] = acc * W2[0 * HH + j];
    r1[j] = acc * W2[1 * HH + j];
    __syncthreads();
    for (int st = 128; st > 0; st >>= 1) {
        if (j < st) { r0[j] += r0[j + st]; r1[j] += r1[j + st]; }
        __syncthreads();
    }
    if (j == 0) {
        out[b * 2 + 0] = r0[0] + b2[0];
        out[b * 2 + 1] = r1[0] + b2[1];
    }
}

extern "C" void kernel_launch(void* const* d_in, const int* in_sizes, int n_in,
                              void* d_out, int out_size, void* d_ws, size_t ws_size,
                              hipStream_t stream) {
    const int* s1 = (const int*)d_in[0];
    const int* s2 = (const int*)d_in[1];
    const float* emb = (const float*)d_in[2];
    const float* W_ih = (const float*)d_in[3];
    const float* W_hh = (const float*)d_in[4];
    const float* b_ih = (const float*)d_in[5];
    const float* b_hh = (const float*)d_in[6];
    const float* h0_1 = (const float*)d_in[7];
    const float* c0_1 = (const float*)d_in[8];
    const float* h0_2 = (const float*)d_in[9];
    const float* c0_2 = (const float*)d_in[10];
    const float* W1 = (const float*)d_in[11];
    const float* b1 = (const float*)d_in[12];
    const float* W2 = (const float*)d_in[13];
    const float* b2 = (const float*)d_in[14];
    float* out = (float*)d_out;

    char* ws = (char*)d_ws;
    size_t off = 0;
    auto alloc = [&](size_t bytes) {
        void* p = ws + off;
        off += (bytes + 255) & ~(size_t)255;
        return p;
    };
    float4* Whp = (float4*)alloc((size_t)HH * HH * sizeof(float4));   // 1MB
    float4* Wip = (float4*)alloc((size_t)EE * HH * sizeof(float4));   // 1MB
    float4* bp = (float4*)alloc(HH * sizeof(float4));
    float* W1T = (float*)alloc((size_t)2 * HH * HH * sizeof(float));  // 512KB
    float* feat = (float*)alloc((size_t)NCH * HH * sizeof(float));    // 512KB
    size_t embw_bytes = (size_t)VV * HH * sizeof(float4);             // 204.8MB
    bool pre = (ws_size >= off + embw_bytes);
    float4* embWp = pre ? (float4*)alloc(embw_bytes) : nullptr;

    pack_w4<<<(HH * HH + 255) / 256, 256, 0, stream>>>(W_ih, Wip, EE);
    pack_w4<<<(HH * HH + 255) / 256, 256, 0, stream>>>(W_hh, Whp, HH);
    pack_b<<<1, 256, 0, stream>>>(b_ih, b_hh, bp);
    transpose_w1<<<(2 * HH * HH + 255) / 256, 256, 0, stream>>>(W1, W1T);

    if (pre) {
        embw_kernel<<<VV / VR, 256, 0, stream>>>(emb, Wip, bp, embWp);
        lstm_kernel<true><<<NWG, 256, 0, stream>>>(s1, s2, emb, Whp, Wip, bp, embWp,
                                                   h0_1, c0_1, h0_2, c0_2, feat);
    } else {
        lstm_kernel<false><<<NWG, 256, 0, stream>>>(s1, s2, emb, Whp, Wip, bp, embWp,
                                                    h0_1, c0_1, h0_2, c0_2, feat);
    }
    head_kernel<<<BB, 256, 0, stream>>>(feat, W1T, b1, W2, b2, out);
}